// Round 1
// baseline (616.489 us; speedup 1.0000x reference)
//
#include <hip/hip_runtime.h>
#include <hip/hip_bf16.h>

// ScaledDotProductAttention: B=64, Lq=Lk=1024, D=64, temperature=8
// out = [output (64*1024*64 fp32) | attn (64*1024*1024 fp32)]

#define LQT 64          // q rows per workgroup
#define KSTRIDE 72      // shorts per row of kbuf/vtbuf (144 B, 16B-aligned)
#define PSTRIDE 68      // floats per row of ptile (272 B, 16B-aligned)

typedef __attribute__((ext_vector_type(8))) short bf16x8;
typedef __attribute__((ext_vector_type(4))) float f32x4;

static __device__ __forceinline__ short f2bf(float f) {
    unsigned u = __builtin_bit_cast(unsigned, f);
    unsigned r = (u + 0x7fffu + ((u >> 16) & 1u)) >> 16;  // RNE
    return (short)r;
}
static __device__ __forceinline__ bf16x8 pack8(float4 a, float4 b) {
    bf16x8 r;
    r[0] = f2bf(a.x); r[1] = f2bf(a.y); r[2] = f2bf(a.z); r[3] = f2bf(a.w);
    r[4] = f2bf(b.x); r[5] = f2bf(b.y); r[6] = f2bf(b.z); r[7] = f2bf(b.w);
    return r;
}

__global__ __launch_bounds__(256) void attn_kernel(
    const float* __restrict__ q, const float* __restrict__ k,
    const float* __restrict__ v, const int* __restrict__ mask,
    float* __restrict__ out, float* __restrict__ attn)
{
    __shared__ unsigned maskbits[64][32];        // 8 KB: [tile q-row][col word]
    __shared__ short kbuf[64 * KSTRIDE];         // 9 KB: K tile [kpos][d] bf16
    __shared__ short vtbuf[64 * KSTRIDE];        // 9 KB: V tile transposed [d][kpos] bf16
    __shared__ float ptile[4 * 16 * PSTRIDE];    // 17 KB: per-wave P round-trip

    const int tid  = threadIdx.x;
    const int w    = tid >> 6;    // wave id 0..3
    const int L    = tid & 63;    // lane
    const int n    = L & 15;
    const int quad = L >> 4;
    const int b    = blockIdx.y;
    const int q0   = blockIdx.x * LQT;
    const long bq  = (long)b * 1024 + q0;   // global row base (q/out/attn/mask)

    // ---------------- Q fragments (A-layout), scaled by 1/8, bf16 ----------------
    // lane holds Q[row = 16w+n][k = quad*8 + j (+32c)]
    const float* qrow = q + (bq + 16 * w + n) * 64 + quad * 8;
    float4 qa0 = ((const float4*)qrow)[0];
    float4 qa1 = ((const float4*)(qrow + 4))[0];
    float4 qb0 = ((const float4*)(qrow + 32))[0];
    float4 qb1 = ((const float4*)(qrow + 36))[0];
    const float sc = 0.125f;  // exact power of two: fold temperature into Q
    qa0.x *= sc; qa0.y *= sc; qa0.z *= sc; qa0.w *= sc;
    qa1.x *= sc; qa1.y *= sc; qa1.z *= sc; qa1.w *= sc;
    qb0.x *= sc; qb0.y *= sc; qb0.z *= sc; qb0.w *= sc;
    qb1.x *= sc; qb1.y *= sc; qb1.z *= sc; qb1.w *= sc;
    bf16x8 qf0 = pack8(qa0, qa1);
    bf16x8 qf1 = pack8(qb0, qb1);

    // ---------------- mask -> bitmask in LDS (mask read exactly once) -------------
    #pragma unroll
    for (int ii = 0; ii < 8; ++ii) {
        int wi  = ii * 256 + tid;          // word index 0..2047
        int row = wi >> 5;                 // tile q-row
        int wc  = wi & 31;                 // which 32-col word
        const int4* mp = (const int4*)(mask + (bq + row) * 1024 + wc * 32);
        unsigned word = 0;
        #pragma unroll
        for (int j = 0; j < 8; ++j) {
            int4 m4 = mp[j];
            word |= (m4.x != 0 ? 1u : 0u) << (4 * j + 0);
            word |= (m4.y != 0 ? 1u : 0u) << (4 * j + 1);
            word |= (m4.z != 0 ? 1u : 0u) << (4 * j + 2);
            word |= (m4.w != 0 ? 1u : 0u) << (4 * j + 3);
        }
        maskbits[row][wc] = word;
    }

    // ---------------- sweep 1: online softmax stats (m, l) ----------------------
    float m_i[4] = {-1e30f, -1e30f, -1e30f, -1e30f};
    float l_i[4] = {0.f, 0.f, 0.f, 0.f};

    for (int kt = 0; kt < 16; ++kt) {
        __syncthreads();
        {   // stage K tile as bf16: row = kpos (tid&63), cols 16w..16w+15
            const float* kr = k + ((long)b * 1024 + kt * 64 + L) * 64 + w * 16;
            float4 k0 = ((const float4*)kr)[0];
            float4 k1 = ((const float4*)kr)[1];
            float4 k2 = ((const float4*)kr)[2];
            float4 k3 = ((const float4*)kr)[3];
            bf16x8* dst = (bf16x8*)&kbuf[L * KSTRIDE + w * 16];
            dst[0] = pack8(k0, k1);
            dst[1] = pack8(k2, k3);
        }
        __syncthreads();

        f32x4 acc[4];
        #pragma unroll
        for (int t = 0; t < 4; ++t) { acc[t][0]=0.f; acc[t][1]=0.f; acc[t][2]=0.f; acc[t][3]=0.f; }
        #pragma unroll
        for (int t = 0; t < 4; ++t) {
            bf16x8 b0 = *(const bf16x8*)&kbuf[(t * 16 + n) * KSTRIDE + quad * 8];
            bf16x8 b1 = *(const bf16x8*)&kbuf[(t * 16 + n) * KSTRIDE + 32 + quad * 8];
            acc[t] = __builtin_amdgcn_mfma_f32_16x16x32_bf16(qf0, b0, acc[t], 0, 0, 0);
            acc[t] = __builtin_amdgcn_mfma_f32_16x16x32_bf16(qf1, b1, acc[t], 0, 0, 0);
        }
        #pragma unroll
        for (int i = 0; i < 4; ++i) {
            int mrow = 16 * w + quad * 4 + i;
            unsigned w0 = maskbits[mrow][kt * 2];
            unsigned w1 = maskbits[mrow][kt * 2 + 1];
            float s0 = ((w0 >> n)        & 1u) ? -1e30f : acc[0][i];
            float s1 = ((w0 >> (16 + n)) & 1u) ? -1e30f : acc[1][i];
            float s2 = ((w1 >> n)        & 1u) ? -1e30f : acc[2][i];
            float s3 = ((w1 >> (16 + n)) & 1u) ? -1e30f : acc[3][i];
            float mt = fmaxf(fmaxf(s0, s1), fmaxf(s2, s3));
            mt = fmaxf(mt, __shfl_xor(mt, 1));
            mt = fmaxf(mt, __shfl_xor(mt, 2));
            mt = fmaxf(mt, __shfl_xor(mt, 4));
            mt = fmaxf(mt, __shfl_xor(mt, 8));
            float mnew = fmaxf(m_i[i], mt);
            float ps = __expf(s0 - mnew) + __expf(s1 - mnew)
                     + __expf(s2 - mnew) + __expf(s3 - mnew);
            ps += __shfl_xor(ps, 1);
            ps += __shfl_xor(ps, 2);
            ps += __shfl_xor(ps, 4);
            ps += __shfl_xor(ps, 8);
            l_i[i] = l_i[i] * __expf(m_i[i] - mnew) + ps;
            m_i[i] = mnew;
        }
    }
    float linv[4];
    #pragma unroll
    for (int i = 0; i < 4; ++i) linv[i] = 1.0f / l_i[i];  // l >= 1 always

    // ---------------- sweep 2: recompute S -> P, write attn, P@V -----------------
    f32x4 oacc[4];
    #pragma unroll
    for (int t = 0; t < 4; ++t) { oacc[t][0]=0.f; oacc[t][1]=0.f; oacc[t][2]=0.f; oacc[t][3]=0.f; }

    float* attn_row = attn + (bq + 16 * w + n) * 1024;

    for (int kt = 0; kt < 16; ++kt) {
        __syncthreads();
        {   // stage K tile (bf16) and V tile transposed (bf16)
            const float* kr = k + ((long)b * 1024 + kt * 64 + L) * 64 + w * 16;
            float4 k0 = ((const float4*)kr)[0];
            float4 k1 = ((const float4*)kr)[1];
            float4 k2 = ((const float4*)kr)[2];
            float4 k3 = ((const float4*)kr)[3];
            bf16x8* dst = (bf16x8*)&kbuf[L * KSTRIDE + w * 16];
            dst[0] = pack8(k0, k1);
            dst[1] = pack8(k2, k3);

            const float* vr = v + ((long)b * 1024 + kt * 64 + L) * 64 + w * 16;
            float4 v0 = ((const float4*)vr)[0];
            float4 v1 = ((const float4*)vr)[1];
            float4 v2 = ((const float4*)vr)[2];
            float4 v3 = ((const float4*)vr)[3];
            float vv[16] = {v0.x, v0.y, v0.z, v0.w, v1.x, v1.y, v1.z, v1.w,
                            v2.x, v2.y, v2.z, v2.w, v3.x, v3.y, v3.z, v3.w};
            #pragma unroll
            for (int dd = 0; dd < 16; ++dd)
                vtbuf[(w * 16 + dd) * KSTRIDE + L] = f2bf(vv[dd]);
        }
        __syncthreads();

        f32x4 acc[4];
        #pragma unroll
        for (int t = 0; t < 4; ++t) { acc[t][0]=0.f; acc[t][1]=0.f; acc[t][2]=0.f; acc[t][3]=0.f; }
        #pragma unroll
        for (int t = 0; t < 4; ++t) {
            bf16x8 b0 = *(const bf16x8*)&kbuf[(t * 16 + n) * KSTRIDE + quad * 8];
            bf16x8 b1 = *(const bf16x8*)&kbuf[(t * 16 + n) * KSTRIDE + 32 + quad * 8];
            acc[t] = __builtin_amdgcn_mfma_f32_16x16x32_bf16(qf0, b0, acc[t], 0, 0, 0);
            acc[t] = __builtin_amdgcn_mfma_f32_16x16x32_bf16(qf1, b1, acc[t], 0, 0, 0);
        }
        // P in C-layout -> LDS (per-wave region), same-wave in-order DS ops
        #pragma unroll
        for (int i = 0; i < 4; ++i) {
            int mrow = 16 * w + quad * 4 + i;
            unsigned w0 = maskbits[mrow][kt * 2];
            unsigned w1 = maskbits[mrow][kt * 2 + 1];
            float s0 = ((w0 >> n)        & 1u) ? -1e30f : acc[0][i];
            float s1 = ((w0 >> (16 + n)) & 1u) ? -1e30f : acc[1][i];
            float s2 = ((w1 >> n)        & 1u) ? -1e30f : acc[2][i];
            float s3 = ((w1 >> (16 + n)) & 1u) ? -1e30f : acc[3][i];
            float* pr = &ptile[(w * 16 + quad * 4 + i) * PSTRIDE];
            pr[n]      = __expf(s0 - m_i[i]) * linv[i];
            pr[16 + n] = __expf(s1 - m_i[i]) * linv[i];
            pr[32 + n] = __expf(s2 - m_i[i]) * linv[i];
            pr[48 + n] = __expf(s3 - m_i[i]) * linv[i];
        }
        // read back in A-layout, write attn, feed P@V
        bf16x8 pf[2];
        #pragma unroll
        for (int c = 0; c < 2; ++c) {
            const float* pp = &ptile[(w * 16 + n) * PSTRIDE + c * 32 + quad * 8];
            float4 p0 = ((const float4*)pp)[0];
            float4 p1 = ((const float4*)pp)[1];
            float* ap = attn_row + kt * 64 + c * 32 + quad * 8;
            ((float4*)ap)[0] = p0;
            ((float4*)ap)[1] = p1;
            pf[c] = pack8(p0, p1);
        }
        #pragma unroll
        for (int t = 0; t < 4; ++t) {
            bf16x8 vb0 = *(const bf16x8*)&vtbuf[(t * 16 + n) * KSTRIDE + quad * 8];
            bf16x8 vb1 = *(const bf16x8*)&vtbuf[(t * 16 + n) * KSTRIDE + 32 + quad * 8];
            oacc[t] = __builtin_amdgcn_mfma_f32_16x16x32_bf16(pf[0], vb0, oacc[t], 0, 0, 0);
            oacc[t] = __builtin_amdgcn_mfma_f32_16x16x32_bf16(pf[1], vb1, oacc[t], 0, 0, 0);
        }
    }

    // ---------------- write O ----------------------------------------------------
    #pragma unroll
    for (int t = 0; t < 4; ++t)
        #pragma unroll
        for (int i = 0; i < 4; ++i)
            out[(bq + 16 * w + quad * 4 + i) * 64 + t * 16 + n] = oacc[t][i];
}

extern "C" void kernel_launch(void* const* d_in, const int* in_sizes, int n_in,
                              void* d_out, int out_size, void* d_ws, size_t ws_size,
                              hipStream_t stream) {
    const float* q    = (const float*)d_in[0];
    const float* k    = (const float*)d_in[1];
    const float* v    = (const float*)d_in[2];
    const int*   mask = (const int*)d_in[3];
    float* out  = (float*)d_out;
    float* attn = out + (long)64 * 1024 * 64;   // tuple: (output, attn)

    dim3 grid(16, 64, 1);   // 16 q-tiles x 64 batches
    dim3 block(256, 1, 1);
    attn_kernel<<<grid, block, 0, stream>>>(q, k, v, mask, out, attn);
}

// Round 2
// 572.017 us; speedup vs baseline: 1.0777x; 1.0777x over previous
//
#include <hip/hip_runtime.h>
#include <hip/hip_bf16.h>

// ScaledDotProductAttention: B=64, Lq=Lk=1024, D=64, temperature=8
// out = [output (64*1024*64 fp32) | attn (64*1024*1024 fp32)]

typedef __attribute__((ext_vector_type(8))) short bf16x8;
typedef __attribute__((ext_vector_type(4))) float f32x4;

#define GLOBAL_AS __attribute__((address_space(1)))
#define LDS_AS    __attribute__((address_space(3)))

static __device__ __forceinline__ short f2bf(float f) {
    unsigned u = __builtin_bit_cast(unsigned, f);
    unsigned r = (u + 0x7fffu + ((u >> 16) & 1u)) >> 16;  // RNE
    return (short)r;
}
static __device__ __forceinline__ float bf2f(short s) {
    unsigned u = ((unsigned)(unsigned short)s) << 16;
    return __builtin_bit_cast(float, u);
}
static __device__ __forceinline__ bf16x8 pack8(float4 a, float4 b) {
    bf16x8 r;
    r[0] = f2bf(a.x); r[1] = f2bf(a.y); r[2] = f2bf(a.z); r[3] = f2bf(a.w);
    r[4] = f2bf(b.x); r[5] = f2bf(b.y); r[6] = f2bf(b.z); r[7] = f2bf(b.w);
    return r;
}

// one wave-wide 1KB async global->LDS copy: lds dest = uniform base + lane*16
static __device__ __forceinline__ void dma16(void* lds, const void* g) {
    __builtin_amdgcn_global_load_lds((const GLOBAL_AS unsigned*)g,
                                     (LDS_AS unsigned*)lds, 16, 0, 0);
}
// stage an 8KB tile (64 rows x 128B), 2 insts per wave
static __device__ __forceinline__ void stage8k(short* lds, const short* g, int w, int L) {
    dma16((void*)(lds + (w * 2 + 0) * 512), (const void*)(g + (w * 2 + 0) * 512 + L * 8));
    dma16((void*)(lds + (w * 2 + 1) * 512), (const void*)(g + (w * 2 + 1) * 512 + L * 8));
}

// XOR bank swizzle: row r (0..63, 64 shorts = 8x16B chunks), chunk c -> c ^ (r&7)
#define KIDX(r, c) ((r) * 64 + ((((c) ^ ((r) & 7))) << 3))

// ---------------------------------------------------------------------------
// pre-pass 1: mask (int32 0/1) -> bitmask, 268MB -> 8MB, via __ballot
__global__ __launch_bounds__(256) void pre_maskpack(const int* __restrict__ mask,
                                                    unsigned long long* __restrict__ bits) {
    const int L = threadIdx.x & 63;
    long gw = ((long)blockIdx.x * 256 + threadIdx.x) >> 6;
    const long nseg = (64L * 1024 * 1024) / 256;  // 262144 segments of 256 cols
    const long step = (long)gridDim.x * 4;
    for (long seg = gw; seg < nseg; seg += step) {
        const int* p = mask + seg * 256;
        unsigned long long b0 = __ballot(p[L] != 0);
        unsigned long long b1 = __ballot(p[64 + L] != 0);
        unsigned long long b2 = __ballot(p[128 + L] != 0);
        unsigned long long b3 = __ballot(p[192 + L] != 0);
        if (L == 0) {
            ulonglong2* d = (ulonglong2*)(bits + seg * 4);
            ulonglong2 t0; t0.x = b0; t0.y = b1;
            ulonglong2 t1; t1.x = b2; t1.y = b3;
            d[0] = t0; d[1] = t1;
        }
    }
}

// pre-pass 2: K fp32 -> bf16, tile-blocked [b*16+kt][kp(64)][8 chunks swizzled]
__global__ __launch_bounds__(256) void pre_kconv(const float* __restrict__ k,
                                                 short* __restrict__ kb) {
    long ci = (long)blockIdx.x * 256 + threadIdx.x;  // 524288 chunks total
    long row = ci >> 3;                              // b*1024 + kp
    int  c   = (int)(ci & 7);
    const float4* s = (const float4*)(k + row * 64 + c * 8);
    float4 a = s[0], bb = s[1];
    int r = (int)(row & 63);
    short* dst = kb + (row >> 6) * 4096 + (long)r * 64 + ((c ^ (r & 7)) << 3);
    *(bf16x8*)dst = pack8(a, bb);
}

// pre-pass 3: V fp32 -> bf16 transposed tiles [b*16+kt][d(64)][kp chunks swizzled]
__global__ __launch_bounds__(256) void pre_vtrans(const float* __restrict__ v,
                                                  short* __restrict__ vt) {
    __shared__ short t[64][72];
    const int bkt = blockIdx.x;        // b*16 + kt
    const int tid = threadIdx.x;
    const int row = tid >> 2;          // kp within tile
    const int cg  = (tid & 3) * 16;    // d start
    const float* src = v + ((long)bkt * 64 + row) * 64 + cg;
    float4 f0 = ((const float4*)src)[0];
    float4 f1 = ((const float4*)src)[1];
    float4 f2 = ((const float4*)src)[2];
    float4 f3 = ((const float4*)src)[3];
    float vv[16] = {f0.x, f0.y, f0.z, f0.w, f1.x, f1.y, f1.z, f1.w,
                    f2.x, f2.y, f2.z, f2.w, f3.x, f3.y, f3.z, f3.w};
    #pragma unroll
    for (int dd = 0; dd < 16; ++dd) t[cg + dd][row] = f2bf(vv[dd]);
    __syncthreads();
    const int d = tid >> 2, c0 = (tid & 3) * 2;
    short* dstrow = vt + (long)bkt * 4096 + d * 64;
    *(int4*)&dstrow[((c0 ^ (d & 7)) << 3)]       = *(int4*)&t[d][c0 * 8];
    *(int4*)&dstrow[(((c0 + 1) ^ (d & 7)) << 3)] = *(int4*)&t[d][c0 * 8 + 8];
}

// ---------------------------------------------------------------------------
// main kernel: all reads via global_load_lds DMA, double-buffered, 1 barrier/iter
__global__ __launch_bounds__(256) void attn_main(
    const float* __restrict__ q, const unsigned* __restrict__ bits,
    const short* __restrict__ kb, const short* __restrict__ vt,
    float* __restrict__ out, float* __restrict__ attn)
{
    __shared__ unsigned maskbits[64 * 32];   // 8 KB
    __shared__ short kbuf[2][64 * 64];       // 16 KB
    __shared__ short vbuf[2][64 * 64];       // 16 KB
    __shared__ short ptile[4][16 * 72];      // 9 KB  (bf16 P round-trip, padded)

    const int tid  = threadIdx.x;
    const int w    = tid >> 6;
    const int L    = tid & 63;
    const int n    = L & 15;
    const int quad = L >> 4;
    const int b    = blockIdx.y;
    const long bq  = (long)b * 1024 + blockIdx.x * 64;

    const short* ktg = kb + (long)b * 65536;   // b*16 tiles * 4096 shorts
    const short* vtg = vt + (long)b * 65536;

    // prologue: DMA mask bits (8KB) + K tile 0
    {
        const unsigned* mg = bits + bq * 32;
        dma16((void*)(maskbits + (w * 2 + 0) * 256), (const void*)(mg + (w * 2 + 0) * 256 + L * 4));
        dma16((void*)(maskbits + (w * 2 + 1) * 256), (const void*)(mg + (w * 2 + 1) * 256 + L * 4));
        stage8k(kbuf[0], ktg, w, L);
    }

    // Q fragments (fp32 load, scaled 1/8, bf16)
    const float* qrow = q + (bq + 16 * w + n) * 64 + quad * 8;
    float4 qa0 = ((const float4*)qrow)[0];
    float4 qa1 = ((const float4*)(qrow + 4))[0];
    float4 qb0 = ((const float4*)(qrow + 32))[0];
    float4 qb1 = ((const float4*)(qrow + 36))[0];
    const float sc = 0.125f;
    qa0.x *= sc; qa0.y *= sc; qa0.z *= sc; qa0.w *= sc;
    qa1.x *= sc; qa1.y *= sc; qa1.z *= sc; qa1.w *= sc;
    qb0.x *= sc; qb0.y *= sc; qb0.z *= sc; qb0.w *= sc;
    qb1.x *= sc; qb1.y *= sc; qb1.z *= sc; qb1.w *= sc;
    bf16x8 qf0 = pack8(qa0, qa1);
    bf16x8 qf1 = pack8(qb0, qb1);

    __syncthreads();

    // ---------------- sweep 1: online softmax stats -------------------------
    float m_i[4] = {-1e30f, -1e30f, -1e30f, -1e30f};
    float l_i[4] = {0.f, 0.f, 0.f, 0.f};

    for (int kt = 0; kt < 16; ++kt) {
        if (kt < 15) stage8k(kbuf[(kt + 1) & 1], ktg + (kt + 1) * 4096, w, L);
        const short* kl = kbuf[kt & 1];
        f32x4 acc[4];
        #pragma unroll
        for (int t = 0; t < 4; ++t) { acc[t][0]=0.f; acc[t][1]=0.f; acc[t][2]=0.f; acc[t][3]=0.f; }
        #pragma unroll
        for (int t = 0; t < 4; ++t) {
            bf16x8 b0 = *(const bf16x8*)&kl[KIDX(t * 16 + n, quad)];
            bf16x8 b1 = *(const bf16x8*)&kl[KIDX(t * 16 + n, 4 + quad)];
            acc[t] = __builtin_amdgcn_mfma_f32_16x16x32_bf16(qf0, b0, acc[t], 0, 0, 0);
            acc[t] = __builtin_amdgcn_mfma_f32_16x16x32_bf16(qf1, b1, acc[t], 0, 0, 0);
        }
        #pragma unroll
        for (int i = 0; i < 4; ++i) {
            int mrow = 16 * w + quad * 4 + i;
            unsigned w0 = maskbits[mrow * 32 + kt * 2];
            unsigned w1 = maskbits[mrow * 32 + kt * 2 + 1];
            float s0 = ((w0 >> n)        & 1u) ? -1e30f : acc[0][i];
            float s1 = ((w0 >> (16 + n)) & 1u) ? -1e30f : acc[1][i];
            float s2 = ((w1 >> n)        & 1u) ? -1e30f : acc[2][i];
            float s3 = ((w1 >> (16 + n)) & 1u) ? -1e30f : acc[3][i];
            float mt = fmaxf(fmaxf(s0, s1), fmaxf(s2, s3));
            mt = fmaxf(mt, __shfl_xor(mt, 1));
            mt = fmaxf(mt, __shfl_xor(mt, 2));
            mt = fmaxf(mt, __shfl_xor(mt, 4));
            mt = fmaxf(mt, __shfl_xor(mt, 8));
            float mnew = fmaxf(m_i[i], mt);
            float ps = __expf(s0 - mnew) + __expf(s1 - mnew)
                     + __expf(s2 - mnew) + __expf(s3 - mnew);
            ps += __shfl_xor(ps, 1);
            ps += __shfl_xor(ps, 2);
            ps += __shfl_xor(ps, 4);
            ps += __shfl_xor(ps, 8);
            l_i[i] = l_i[i] * __expf(m_i[i] - mnew) + ps;
            m_i[i] = mnew;
        }
        __syncthreads();
    }
    float linv[4];
    #pragma unroll
    for (int i = 0; i < 4; ++i) linv[i] = 1.0f / l_i[i];

    // ---------------- sweep 2: recompute S -> P, write attn, P@V ------------
    f32x4 oacc[4];
    #pragma unroll
    for (int t = 0; t < 4; ++t) { oacc[t][0]=0.f; oacc[t][1]=0.f; oacc[t][2]=0.f; oacc[t][3]=0.f; }

    stage8k(kbuf[0], ktg, w, L);
    stage8k(vbuf[0], vtg, w, L);
    __syncthreads();

    float* attn_row = attn + (bq + 16 * w + n) * 1024;

    for (int kt = 0; kt < 16; ++kt) {
        if (kt < 15) {
            stage8k(kbuf[(kt + 1) & 1], ktg + (kt + 1) * 4096, w, L);
            stage8k(vbuf[(kt + 1) & 1], vtg + (kt + 1) * 4096, w, L);
        }
        const short* kl = kbuf[kt & 1];
        const short* vl = vbuf[kt & 1];
        f32x4 acc[4];
        #pragma unroll
        for (int t = 0; t < 4; ++t) { acc[t][0]=0.f; acc[t][1]=0.f; acc[t][2]=0.f; acc[t][3]=0.f; }
        #pragma unroll
        for (int t = 0; t < 4; ++t) {
            bf16x8 b0 = *(const bf16x8*)&kl[KIDX(t * 16 + n, quad)];
            bf16x8 b1 = *(const bf16x8*)&kl[KIDX(t * 16 + n, 4 + quad)];
            acc[t] = __builtin_amdgcn_mfma_f32_16x16x32_bf16(qf0, b0, acc[t], 0, 0, 0);
            acc[t] = __builtin_amdgcn_mfma_f32_16x16x32_bf16(qf1, b1, acc[t], 0, 0, 0);
        }
        short* pw = ptile[w];
        #pragma unroll
        for (int i = 0; i < 4; ++i) {
            int mrow = 16 * w + quad * 4 + i;
            unsigned w0 = maskbits[mrow * 32 + kt * 2];
            unsigned w1 = maskbits[mrow * 32 + kt * 2 + 1];
            float s0 = ((w0 >> n)        & 1u) ? -1e30f : acc[0][i];
            float s1 = ((w0 >> (16 + n)) & 1u) ? -1e30f : acc[1][i];
            float s2 = ((w1 >> n)        & 1u) ? -1e30f : acc[2][i];
            float s3 = ((w1 >> (16 + n)) & 1u) ? -1e30f : acc[3][i];
            short* pr = &pw[(quad * 4 + i) * 72];
            pr[n]      = f2bf(__expf(s0 - m_i[i]) * linv[i]);
            pr[16 + n] = f2bf(__expf(s1 - m_i[i]) * linv[i]);
            pr[32 + n] = f2bf(__expf(s2 - m_i[i]) * linv[i]);
            pr[48 + n] = f2bf(__expf(s3 - m_i[i]) * linv[i]);
        }
        // read back in A-layout (same wave, in-order LDS pipe)
        bf16x8 pf0 = *(const bf16x8*)&pw[n * 72 + quad * 8];
        bf16x8 pf1 = *(const bf16x8*)&pw[n * 72 + 32 + quad * 8];
        // write attn (widened bf16 -> fp32, coalesced float4)
        float* ap = attn_row + kt * 64;
        float4 f0, f1, g0, g1;
        f0.x = bf2f(pf0[0]); f0.y = bf2f(pf0[1]); f0.z = bf2f(pf0[2]); f0.w = bf2f(pf0[3]);
        f1.x = bf2f(pf0[4]); f1.y = bf2f(pf0[5]); f1.z = bf2f(pf0[6]); f1.w = bf2f(pf0[7]);
        g0.x = bf2f(pf1[0]); g0.y = bf2f(pf1[1]); g0.z = bf2f(pf1[2]); g0.w = bf2f(pf1[3]);
        g1.x = bf2f(pf1[4]); g1.y = bf2f(pf1[5]); g1.z = bf2f(pf1[6]); g1.w = bf2f(pf1[7]);
        *(float4*)(ap + quad * 8)          = f0;
        *(float4*)(ap + quad * 8 + 4)      = f1;
        *(float4*)(ap + 32 + quad * 8)     = g0;
        *(float4*)(ap + 32 + quad * 8 + 4) = g1;
        // P @ V
        #pragma unroll
        for (int t = 0; t < 4; ++t) {
            bf16x8 v0 = *(const bf16x8*)&vl[KIDX(t * 16 + n, quad)];
            bf16x8 v1 = *(const bf16x8*)&vl[KIDX(t * 16 + n, 4 + quad)];
            oacc[t] = __builtin_amdgcn_mfma_f32_16x16x32_bf16(pf0, v0, oacc[t], 0, 0, 0);
            oacc[t] = __builtin_amdgcn_mfma_f32_16x16x32_bf16(pf1, v1, oacc[t], 0, 0, 0);
        }
        __syncthreads();
    }

    #pragma unroll
    for (int t = 0; t < 4; ++t)
        #pragma unroll
        for (int i = 0; i < 4; ++i)
            out[(bq + 16 * w + quad * 4 + i) * 64 + t * 16 + n] = oacc[t][i];
}

// ---------------------------------------------------------------------------
// fallback (round-1 kernel) for small ws_size
#define KSTRIDE 72
#define PSTRIDE 68
__global__ __launch_bounds__(256) void attn_fallback(
    const float* __restrict__ q, const float* __restrict__ k,
    const float* __restrict__ v, const int* __restrict__ mask,
    float* __restrict__ out, float* __restrict__ attn)
{
    __shared__ unsigned maskbits[64][32];
    __shared__ short kbuf[64 * KSTRIDE];
    __shared__ short vtbuf[64 * KSTRIDE];
    __shared__ float ptile[4 * 16 * PSTRIDE];

    const int tid  = threadIdx.x;
    const int w    = tid >> 6;
    const int L    = tid & 63;
    const int n    = L & 15;
    const int quad = L >> 4;
    const int b    = blockIdx.y;
    const long bq  = (long)b * 1024 + blockIdx.x * 64;

    const float* qrow = q + (bq + 16 * w + n) * 64 + quad * 8;
    float4 qa0 = ((const float4*)qrow)[0];
    float4 qa1 = ((const float4*)(qrow + 4))[0];
    float4 qb0 = ((const float4*)(qrow + 32))[0];
    float4 qb1 = ((const float4*)(qrow + 36))[0];
    const float sc = 0.125f;
    qa0.x *= sc; qa0.y *= sc; qa0.z *= sc; qa0.w *= sc;
    qa1.x *= sc; qa1.y *= sc; qa1.z *= sc; qa1.w *= sc;
    qb0.x *= sc; qb0.y *= sc; qb0.z *= sc; qb0.w *= sc;
    qb1.x *= sc; qb1.y *= sc; qb1.z *= sc; qb1.w *= sc;
    bf16x8 qf0 = pack8(qa0, qa1);
    bf16x8 qf1 = pack8(qb0, qb1);

    #pragma unroll
    for (int ii = 0; ii < 8; ++ii) {
        int wi  = ii * 256 + tid;
        int row = wi >> 5;
        int wc  = wi & 31;
        const int4* mp = (const int4*)(mask + (bq + row) * 1024 + wc * 32);
        unsigned word = 0;
        #pragma unroll
        for (int j = 0; j < 8; ++j) {
            int4 m4 = mp[j];
            word |= (m4.x != 0 ? 1u : 0u) << (4 * j + 0);
            word |= (m4.y != 0 ? 1u : 0u) << (4 * j + 1);
            word |= (m4.z != 0 ? 1u : 0u) << (4 * j + 2);
            word |= (m4.w != 0 ? 1u : 0u) << (4 * j + 3);
        }
        maskbits[row][wc] = word;
    }

    float m_i[4] = {-1e30f, -1e30f, -1e30f, -1e30f};
    float l_i[4] = {0.f, 0.f, 0.f, 0.f};

    for (int kt = 0; kt < 16; ++kt) {
        __syncthreads();
        {
            const float* kr = k + ((long)b * 1024 + kt * 64 + L) * 64 + w * 16;
            float4 k0 = ((const float4*)kr)[0];
            float4 k1 = ((const float4*)kr)[1];
            float4 k2 = ((const float4*)kr)[2];
            float4 k3 = ((const float4*)kr)[3];
            bf16x8* dst = (bf16x8*)&kbuf[L * KSTRIDE + w * 16];
            dst[0] = pack8(k0, k1);
            dst[1] = pack8(k2, k3);
        }
        __syncthreads();
        f32x4 acc[4];
        #pragma unroll
        for (int t = 0; t < 4; ++t) { acc[t][0]=0.f; acc[t][1]=0.f; acc[t][2]=0.f; acc[t][3]=0.f; }
        #pragma unroll
        for (int t = 0; t < 4; ++t) {
            bf16x8 b0 = *(const bf16x8*)&kbuf[(t * 16 + n) * KSTRIDE + quad * 8];
            bf16x8 b1 = *(const bf16x8*)&kbuf[(t * 16 + n) * KSTRIDE + 32 + quad * 8];
            acc[t] = __builtin_amdgcn_mfma_f32_16x16x32_bf16(qf0, b0, acc[t], 0, 0, 0);
            acc[t] = __builtin_amdgcn_mfma_f32_16x16x32_bf16(qf1, b1, acc[t], 0, 0, 0);
        }
        #pragma unroll
        for (int i = 0; i < 4; ++i) {
            int mrow = 16 * w + quad * 4 + i;
            unsigned w0 = maskbits[mrow][kt * 2];
            unsigned w1 = maskbits[mrow][kt * 2 + 1];
            float s0 = ((w0 >> n)        & 1u) ? -1e30f : acc[0][i];
            float s1 = ((w0 >> (16 + n)) & 1u) ? -1e30f : acc[1][i];
            float s2 = ((w1 >> n)        & 1u) ? -1e30f : acc[2][i];
            float s3 = ((w1 >> (16 + n)) & 1u) ? -1e30f : acc[3][i];
            float mt = fmaxf(fmaxf(s0, s1), fmaxf(s2, s3));
            mt = fmaxf(mt, __shfl_xor(mt, 1));
            mt = fmaxf(mt, __shfl_xor(mt, 2));
            mt = fmaxf(mt, __shfl_xor(mt, 4));
            mt = fmaxf(mt, __shfl_xor(mt, 8));
            float mnew = fmaxf(m_i[i], mt);
            float ps = __expf(s0 - mnew) + __expf(s1 - mnew)
                     + __expf(s2 - mnew) + __expf(s3 - mnew);
            ps += __shfl_xor(ps, 1);
            ps += __shfl_xor(ps, 2);
            ps += __shfl_xor(ps, 4);
            ps += __shfl_xor(ps, 8);
            l_i[i] = l_i[i] * __expf(m_i[i] - mnew) + ps;
            m_i[i] = mnew;
        }
    }
    float linv[4];
    #pragma unroll
    for (int i = 0; i < 4; ++i) linv[i] = 1.0f / l_i[i];

    f32x4 oacc[4];
    #pragma unroll
    for (int t = 0; t < 4; ++t) { oacc[t][0]=0.f; oacc[t][1]=0.f; oacc[t][2]=0.f; oacc[t][3]=0.f; }
    float* attn_row = attn + (bq + 16 * w + n) * 1024;

    for (int kt = 0; kt < 16; ++kt) {
        __syncthreads();
        {
            const float* kr = k + ((long)b * 1024 + kt * 64 + L) * 64 + w * 16;
            float4 k0 = ((const float4*)kr)[0];
            float4 k1 = ((const float4*)kr)[1];
            float4 k2 = ((const float4*)kr)[2];
            float4 k3 = ((const float4*)kr)[3];
            bf16x8* dst = (bf16x8*)&kbuf[L * KSTRIDE + w * 16];
            dst[0] = pack8(k0, k1);
            dst[1] = pack8(k2, k3);
            const float* vr = v + ((long)b * 1024 + kt * 64 + L) * 64 + w * 16;
            float4 v0 = ((const float4*)vr)[0];
            float4 v1 = ((const float4*)vr)[1];
            float4 v2 = ((const float4*)vr)[2];
            float4 v3 = ((const float4*)vr)[3];
            float vv[16] = {v0.x, v0.y, v0.z, v0.w, v1.x, v1.y, v1.z, v1.w,
                            v2.x, v2.y, v2.z, v2.w, v3.x, v3.y, v3.z, v3.w};
            #pragma unroll
            for (int dd = 0; dd < 16; ++dd)
                vtbuf[(w * 16 + dd) * KSTRIDE + L] = f2bf(vv[dd]);
        }
        __syncthreads();
        f32x4 acc[4];
        #pragma unroll
        for (int t = 0; t < 4; ++t) { acc[t][0]=0.f; acc[t][1]=0.f; acc[t][2]=0.f; acc[t][3]=0.f; }
        #pragma unroll
        for (int t = 0; t < 4; ++t) {
            bf16x8 b0 = *(const bf16x8*)&kbuf[(t * 16 + n) * KSTRIDE + quad * 8];
            bf16x8 b1 = *(const bf16x8*)&kbuf[(t * 16 + n) * KSTRIDE + 32 + quad * 8];
            acc[t] = __builtin_amdgcn_mfma_f32_16x16x32_bf16(qf0, b0, acc[t], 0, 0, 0);
            acc[t] = __builtin_amdgcn_mfma_f32_16x16x32_bf16(qf1, b1, acc[t], 0, 0, 0);
        }
        #pragma unroll
        for (int i = 0; i < 4; ++i) {
            int mrow = 16 * w + quad * 4 + i;
            unsigned w0 = maskbits[mrow][kt * 2];
            unsigned w1 = maskbits[mrow][kt * 2 + 1];
            float s0 = ((w0 >> n)        & 1u) ? -1e30f : acc[0][i];
            float s1 = ((w0 >> (16 + n)) & 1u) ? -1e30f : acc[1][i];
            float s2 = ((w1 >> n)        & 1u) ? -1e30f : acc[2][i];
            float s3 = ((w1 >> (16 + n)) & 1u) ? -1e30f : acc[3][i];
            float* pr = &ptile[(w * 16 + quad * 4 + i) * PSTRIDE];
            pr[n]      = __expf(s0 - m_i[i]) * linv[i];
            pr[16 + n] = __expf(s1 - m_i[i]) * linv[i];
            pr[32 + n] = __expf(s2 - m_i[i]) * linv[i];
            pr[48 + n] = __expf(s3 - m_i[i]) * linv[i];
        }
        bf16x8 pf[2];
        #pragma unroll
        for (int c = 0; c < 2; ++c) {
            const float* pp = &ptile[(w * 16 + n) * PSTRIDE + c * 32 + quad * 8];
            float4 p0 = ((const float4*)pp)[0];
            float4 p1 = ((const float4*)pp)[1];
            float* ap = attn_row + kt * 64 + c * 32 + quad * 8;
            ((float4*)ap)[0] = p0;
            ((float4*)ap)[1] = p1;
            pf[c] = pack8(p0, p1);
        }
        #pragma unroll
        for (int t = 0; t < 4; ++t) {
            bf16x8 vb0 = *(const bf16x8*)&vtbuf[(t * 16 + n) * KSTRIDE + quad * 8];
            bf16x8 vb1 = *(const bf16x8*)&vtbuf[(t * 16 + n) * KSTRIDE + 32 + quad * 8];
            oacc[t] = __builtin_amdgcn_mfma_f32_16x16x32_bf16(pf[0], vb0, oacc[t], 0, 0, 0);
            oacc[t] = __builtin_amdgcn_mfma_f32_16x16x32_bf16(pf[1], vb1, oacc[t], 0, 0, 0);
        }
    }
    #pragma unroll
    for (int t = 0; t < 4; ++t)
        #pragma unroll
        for (int i = 0; i < 4; ++i)
            out[(bq + 16 * w + quad * 4 + i) * 64 + t * 16 + n] = oacc[t][i];
}

extern "C" void kernel_launch(void* const* d_in, const int* in_sizes, int n_in,
                              void* d_out, int out_size, void* d_ws, size_t ws_size,
                              hipStream_t stream) {
    const float* q    = (const float*)d_in[0];
    const float* k    = (const float*)d_in[1];
    const float* v    = (const float*)d_in[2];
    const int*   mask = (const int*)d_in[3];
    float* out  = (float*)d_out;
    float* attn = out + (long)64 * 1024 * 64;

    dim3 grid(16, 64, 1);
    dim3 block(256, 1, 1);

    const size_t need = (size_t)24 << 20;  // 8MB bits + 8MB Kbf16 + 8MB Vt bf16
    if (ws_size >= need) {
        unsigned char* ws = (unsigned char*)d_ws;
        unsigned long long* bits64 = (unsigned long long*)ws;
        unsigned* bits = (unsigned*)ws;
        short* kbw = (short*)(ws + ((size_t)8 << 20));
        short* vtw = (short*)(ws + ((size_t)16 << 20));
        pre_maskpack<<<2048, 256, 0, stream>>>(mask, bits64);
        pre_kconv<<<2048, 256, 0, stream>>>(k, kbw);
        pre_vtrans<<<1024, 256, 0, stream>>>(v, vtw);
        attn_main<<<grid, block, 0, stream>>>(q, bits, kbw, vtw, out, attn);
    } else {
        attn_fallback<<<grid, block, 0, stream>>>(q, k, v, mask, out, attn);
    }
}